// Round 16
// baseline (86.897 us; speedup 1.0000x reference)
//
#include <hip/hip_runtime.h>
#include <math.h>

#define LQ 1024
#define RS 512          // H*E floats between consecutive l in [B,L,H,E]
#define PJ 26           // padded j-stride for P
#define NP 32
#define ASCALE 0.18033688f   // 0.125 * log2(e)  -> softmax computed in base-2 domain

typedef __attribute__((ext_vector_type(4))) float f32x4;
typedef __attribute__((ext_vector_type(8))) short short8x;

// packed f32x2 -> bf16x2 (RNE) in one VALU op; no HIP API/builtin on gfx950 (T12/m240)
__device__ __forceinline__ unsigned pk2(float a, float b) {
  unsigned r;
  asm("v_cvt_pk_bf16_f32 %0, %1, %2" : "=v"(r) : "v"(a), "v"(b));
  return r;
}

// swizzled LDS byte address for [rows][64 bf16], row stride 128B
__device__ __forceinline__ int swz(int row, int bc) {
  return row * 128 + (bc ^ ((row & 7) << 4));
}
// VT variant: spreads banks when write-rows differ by small strides
__device__ __forceinline__ int swzVT(int row, int bc) {
  return row * 128 + (bc ^ ((((row >> 3) ^ row) & 7) << 4));
}

// P[pair, l, j] = (scale*log2e) * dot(x[b,l,h,:], rel_k_table[j,:])
__global__ __launch_bounds__(256) void k_relproj(const float* __restrict__ x,
                                                 const float* __restrict__ relk,
                                                 float* __restrict__ P) {
  __shared__ float rk[25][68];
  __shared__ float xs[64][68];
  const int tid = threadIdx.x;
  const int pair = blockIdx.y, l0 = blockIdx.x * 64;
  const int b = pair >> 3, h = pair & 7;
  for (int i = tid; i < 25 * 64; i += 256) rk[i >> 6][i & 63] = relk[i] * ASCALE;
  const int row = tid >> 2, q = tid & 3;
  const float* xr = x + (size_t)b * 524288 + (size_t)(l0 + row) * RS + h * 64 + q * 16;
#pragma unroll
  for (int i = 0; i < 4; ++i) {
    float4 a = *(const float4*)(xr + i * 4);
    xs[row][q * 16 + i * 4 + 0] = a.x; xs[row][q * 16 + i * 4 + 1] = a.y;
    xs[row][q * 16 + i * 4 + 2] = a.z; xs[row][q * 16 + i * 4 + 3] = a.w;
  }
  __syncthreads();
  float* Pr = P + ((size_t)pair * LQ + l0 + row) * PJ;
  for (int j = q; j < 25; j += 4) {
    float acc = 0.f;
#pragma unroll
    for (int e = 0; e < 64; ++e) acc += xs[row][e] * rk[j][e];
    Pr[j] = acc;
  }
}

// 512-thread blocks: 8 waves, ONE 16-row strip per wave (128 rows/block).
// SWAPPED QK: accS[ct][r] = T[s = t*64+ct*16+rg*4+r, l = l0+wv*16+col16].
// fast tile  <=>  rel < -74 || rel > 26   (rel = t*64 - l0 - wv*16)
// MODE 0: A=x*ASC, B=y, V=v_y, tab=rel_vy, bias=P[l][j]
// MODE 1: A=y*ASC, B=x, V=v_x, tab=rel_vx, bias=P[s][24-j]; j=clip(s-l,-12,12)+12
__global__ __launch_bounds__(512, 2) void k_fused(
    const float* __restrict__ x, const float* __restrict__ y,
    const float* __restrict__ vx, const float* __restrict__ vy,
    const float* __restrict__ relvx, const float* __restrict__ relvy,
    const float* __restrict__ P_g, float* __restrict__ out_g) {
  __shared__ __align__(16) char U[16384];      // A-stage -> 8 per-wave E tiles -> tab
  __shared__ __align__(16) char Bb[2][8192];
  __shared__ __align__(16) char Vb[2][8192];
  __shared__ float W[128 * PJ];

  const int tid = threadIdx.x;
  // bijective remap: p = bx*64 + g  => the 8 blocks of group g share p%8 (same XCD)
  const int p = blockIdx.x;
  const int g = p & 63, bx = p >> 6;        // bx in 0..7
  const int pair = g & 31, mode = g >> 5;
  const int b = pair >> 3, h = pair & 7;
  const int l0 = bx * 128;

  const float* Af = mode ? y : x;
  const float* Bl = mode ? x : y;
  const float* Vv = mode ? vx : vy;
  const float* tb = mode ? relvx : relvy;
  float* outp = out_g + (mode ? 2097152 : 0);

  const float* abase = Af + (size_t)b * 524288 + h * 64;
  const float* bbase = Bl + (size_t)b * 524288 + h * 64;
  const float* vbase = Vv + (size_t)b * 524288 + h * 64;
  const float* Pbase = P_g + (size_t)pair * LQ * PJ;
  float* outb = outp + (size_t)b * 524288 + h * 64;

  const int rowA = tid >> 2, qA = tid & 3;     // A staging: 128 rows, 16 floats/thread
  const int rowB = tid >> 3, qB = tid & 7;     // B staging: 64 rows, 8 floats/thread
  const int vq = tid & 31, vs2 = tid >> 5;     // V staging: d-pair vq*2, s-quad vs2*4

  // ---- prologue: stage A(128 rows, U), B0, VT0; zero W ----
  {
    const float* s = abase + (size_t)(l0 + rowA) * RS + qA * 16;
#pragma unroll
    for (int hh = 0; hh < 2; ++hh) {
      float4 a = *(const float4*)(s + hh * 8);
      float4 c = *(const float4*)(s + hh * 8 + 4);
      uint4 u;
      u.x = pk2(a.x * ASCALE, a.y * ASCALE); u.y = pk2(a.z * ASCALE, a.w * ASCALE);
      u.z = pk2(c.x * ASCALE, c.y * ASCALE); u.w = pk2(c.z * ASCALE, c.w * ASCALE);
      *(uint4*)(U + swz(rowA, qA * 32 + hh * 16)) = u;
    }
    const float* sb2 = bbase + (size_t)rowB * RS + qB * 8;
    float4 a = *(const float4*)(sb2);
    float4 c = *(const float4*)(sb2 + 4);
    uint4 u;
    u.x = pk2(a.x, a.y); u.y = pk2(a.z, a.w);
    u.z = pk2(c.x, c.y); u.w = pk2(c.z, c.w);
    *(uint4*)(Bb[0] + swz(rowB, qB * 16)) = u;

    const float* sv = vbase + (size_t)(vs2 * 4) * RS + vq * 2;
    float2 r0 = *(const float2*)(sv);
    float2 r1 = *(const float2*)(sv + RS);
    float2 r2 = *(const float2*)(sv + 2 * RS);
    float2 r3 = *(const float2*)(sv + 3 * RS);
    uint2 w2;
    w2.x = pk2(r0.x, r1.x); w2.y = pk2(r2.x, r3.x);
    *(uint2*)(Vb[0] + swzVT(vq * 2 + 0, vs2 * 8)) = w2;
    w2.x = pk2(r0.y, r1.y); w2.y = pk2(r2.y, r3.y);
    *(uint2*)(Vb[0] + swzVT(vq * 2 + 1, vs2 * 8)) = w2;
  }
  for (int i = tid; i < 128 * PJ; i += 512) W[i] = 0.f;
  __syncthreads();

  const int lane = tid & 63, wv = tid >> 6;
  const int col16 = lane & 15, rg = lane >> 4;
  char* ea = U + wv * 2048;   // per-wave E tile [16 l][64 s] bf16

  // A fragments (read BEFORE E tiles overwrite U)
  short8x af0 = *(const short8x*)(U + swz(wv * 16 + col16, rg * 16));
  short8x af1 = *(const short8x*)(U + swz(wv * 16 + col16, 64 + rg * 16));

  // lane-l bias (mode 0)
  const int lloc = wv * 16 + col16;
  const float* ProwB = Pbase + (size_t)(l0 + lloc) * PJ;
  float bL = 0.f, bR = 0.f;
  if (mode == 0) { bL = ProwB[0]; bR = ProwB[24]; }
  __syncthreads();   // af reads drained before any wave writes E tiles

  f32x4 accO[4];
  float wl = 0.f, wr = 0.f;
  const f32x4 z4 = {0.f, 0.f, 0.f, 0.f};
#pragma unroll
  for (int dt = 0; dt < 4; ++dt) accO[dt] = z4;

  for (int t = 0; t < 16; ++t) {
    const int cb = t & 1, nb = cb ^ 1;
    const int rel = t * 64 - l0 - wv * 16;
    const bool fast = (rel < -74 || rel > 26);

    // ---- issue next-tile B and V loads FIRST (consumed at end of step) ----
    float4 pb0, pb1;
    float2 pv0, pv1, pv2, pv3;
    if (t < 15) {
      const float* s = bbase + (size_t)((t + 1) * 64 + rowB) * RS + qB * 8;
      pb0 = *(const float4*)(s);
      pb1 = *(const float4*)(s + 4);
      const float* sv2 = vbase + (size_t)((t + 1) * 64 + vs2 * 4) * RS + vq * 2;
      pv0 = *(const float2*)(sv2);
      pv1 = *(const float2*)(sv2 + RS);
      pv2 = *(const float2*)(sv2 + 2 * RS);
      pv3 = *(const float2*)(sv2 + 3 * RS);
    }

    // ---- mode-1 fast-path bias (s-dependent; hoisted so latency hides under QK) ----
    float biasf[16];
    if (mode == 1 && fast) {
      const bool right = rel > 0;
#pragma unroll
      for (int ct = 0; ct < 4; ++ct)
#pragma unroll
        for (int r = 0; r < 4; ++r)
          biasf[ct * 4 + r] =
              Pbase[(size_t)(t * 64 + ct * 16 + rg * 4 + r) * PJ + (right ? 0 : 24)];
    }

    // ---- QK (swapped): accS[ct][r] = T[s = ct*16+rg*4+r, l = col16] ----
    f32x4 accS[4];
    const char* bB = Bb[cb];
#pragma unroll
    for (int ct = 0; ct < 4; ++ct) {
      short8x bf0 = *(const short8x*)(bB + swz(ct * 16 + col16, rg * 16));
      short8x bf1 = *(const short8x*)(bB + swz(ct * 16 + col16, 64 + rg * 16));
      f32x4 tacc = __builtin_amdgcn_mfma_f32_16x16x32_bf16(bf0, af0, z4, 0, 0, 0);
      accS[ct] = __builtin_amdgcn_mfma_f32_16x16x32_bf16(bf1, af1, tacc, 0, 0, 0);
    }

    // ---- epilogue: bias, exp2, bucket sums, E -> own-wave LDS (b64 writes) ----
    if (fast) {
      const bool right = rel > 0;
      const float b0 = right ? bR : bL;   // mode 0: lane-scalar bias
#pragma unroll
      for (int ct = 0; ct < 4; ++ct) {
        float e0 = __builtin_exp2f(accS[ct][0] + (mode ? biasf[ct * 4 + 0] : b0));
        float e1 = __builtin_exp2f(accS[ct][1] + (mode ? biasf[ct * 4 + 1] : b0));
        float e2 = __builtin_exp2f(accS[ct][2] + (mode ? biasf[ct * 4 + 2] : b0));
        float e3 = __builtin_exp2f(accS[ct][3] + (mode ? biasf[ct * 4 + 3] : b0));
        float s4 = (e0 + e1) + (e2 + e3);
        if (right) wr += s4; else wl += s4;
        uint2 w2; w2.x = pk2(e0, e1); w2.y = pk2(e2, e3);
        *(uint2*)(ea + swz(col16, ct * 32 + rg * 8)) = w2;
      }
    } else {
#pragma unroll
      for (int ct = 0; ct < 4; ++ct) {
        float e[4];
#pragma unroll
        for (int r = 0; r < 4; ++r) {
          const int sl = ct * 16 + rg * 4 + r;
          const int d = rel + sl - col16;
          const int j = (d < -12 ? -12 : (d > 12 ? 12 : d)) + 12;
          const float bias = (mode == 0) ? ProwB[j]
                                         : Pbase[(size_t)(t * 64 + sl) * PJ + (24 - j)];
          e[r] = __builtin_exp2f(accS[ct][r] + bias);
          if (d <= -12) wl += e[r];
          else if (d >= 12) wr += e[r];
          else W[lloc * PJ + (d + 12)] = e[r];   // unique (l,j), j in [1,23]
        }
        uint2 w2; w2.x = pk2(e[0], e[1]); w2.y = pk2(e[2], e[3]);
        *(uint2*)(ea + swz(col16, ct * 32 + rg * 8)) = w2;
      }
    }

    // ---- wave-local E handoff (EA is per-wave; rule #18 pattern) ----
    __builtin_amdgcn_sched_barrier(0);
    asm volatile("s_waitcnt lgkmcnt(0)" ::: "memory");
    __builtin_amdgcn_sched_barrier(0);

    // ---- AV: O += E·V ----
    const char* vB = Vb[cb];
    short8x ef0 = *(const short8x*)(ea + swz(col16, rg * 16));
    short8x ef1 = *(const short8x*)(ea + swz(col16, 64 + rg * 16));
#pragma unroll
    for (int dt = 0; dt < 4; ++dt) {
      short8x v0 = *(const short8x*)(vB + swzVT(dt * 16 + col16, rg * 16));
      short8x v1 = *(const short8x*)(vB + swzVT(dt * 16 + col16, 64 + rg * 16));
      f32x4 tacc = __builtin_amdgcn_mfma_f32_16x16x32_bf16(ef0, v0, accO[dt], 0, 0, 0);
      accO[dt] = __builtin_amdgcn_mfma_f32_16x16x32_bf16(ef1, v1, tacc, 0, 0, 0);
    }

    // ---- write staged B,V -> nb (loads had the whole step to land) ----
    if (t < 15) {
      uint4 u;
      u.x = pk2(pb0.x, pb0.y); u.y = pk2(pb0.z, pb0.w);
      u.z = pk2(pb1.x, pb1.y); u.w = pk2(pb1.z, pb1.w);
      *(uint4*)(Bb[nb] + swz(rowB, qB * 16)) = u;
      uint2 w2;
      w2.x = pk2(pv0.x, pv1.x); w2.y = pk2(pv2.x, pv3.x);
      *(uint2*)(Vb[nb] + swzVT(vq * 2 + 0, vs2 * 8)) = w2;
      w2.x = pk2(pv0.y, pv1.y); w2.y = pk2(pv2.y, pv3.y);
      *(uint2*)(Vb[nb] + swzVT(vq * 2 + 1, vs2 * 8)) = w2;
    }
    __syncthreads();  // single barrier per step
  }

  // ---- tab into U (E region dead now) ----
  float* tabf = (float*)U;
  for (int i = tid; i < 25 * 64; i += 512) tabf[i] = tb[i];
  __syncthreads();

  // ---- reduce wl/wr across rg groups (lanes sharing col16) ----
  wl += __shfl_xor(wl, 16); wl += __shfl_xor(wl, 32);
  wr += __shfl_xor(wr, 16); wr += __shfl_xor(wr, 32);
  // redistribute to output-row lanes: row rg*4+r lives at wave-lane (rg*4+r)
  float wlR[4], wrR[4];
#pragma unroll
  for (int r = 0; r < 4; ++r) {
    const int src = rg * 4 + r;
    wlR[r] = __shfl(wl, src);
    wrR[r] = __shfl(wr, src);
  }

  // tails (j=0, j=24)
#pragma unroll
  for (int dt = 0; dt < 4; ++dt) {
    const int dd = dt * 16 + col16;
    const float t0 = tabf[dd], t24 = tabf[24 * 64 + dd];
#pragma unroll
    for (int r = 0; r < 4; ++r) accO[dt][r] += wlR[r] * t0 + wrR[r] * t24;
  }
  // interior j: shared tab reads across r, shared W reads across dt; also row-sums
  float wsum[4] = {0.f, 0.f, 0.f, 0.f};
#pragma unroll 4
  for (int j = 1; j < 24; ++j) {
    float tj[4];
#pragma unroll
    for (int dt = 0; dt < 4; ++dt) tj[dt] = tabf[j * 64 + dt * 16 + col16];
#pragma unroll
    for (int r = 0; r < 4; ++r) {
      const float w = W[(wv * 16 + rg * 4 + r) * PJ + j];
      wsum[r] += w;
#pragma unroll
      for (int dt = 0; dt < 4; ++dt) accO[dt][r] += w * tj[dt];
    }
  }
  float inv[4];
#pragma unroll
  for (int r = 0; r < 4; ++r) inv[r] = 1.f / (wlR[r] + wrR[r] + wsum[r]);

#pragma unroll
  for (int dt = 0; dt < 4; ++dt) {
#pragma unroll
    for (int r = 0; r < 4; ++r) {
      const int row = wv * 16 + rg * 4 + r;
      outb[(size_t)(l0 + row) * RS + dt * 16 + col16] = accO[dt][r] * inv[r];
    }
  }
}

extern "C" void kernel_launch(void* const* d_in, const int* in_sizes, int n_in,
                              void* d_out, int out_size, void* d_ws, size_t ws_size,
                              hipStream_t stream) {
  const float* x = (const float*)d_in[0];
  const float* y = (const float*)d_in[1];
  const float* vx = (const float*)d_in[2];
  const float* vy = (const float*)d_in[3];
  const float* relk = (const float*)d_in[4];
  const float* relvx = (const float*)d_in[5];
  const float* relvy = (const float*)d_in[6];
  float* out = (float*)d_out;

  float* P = (float*)d_ws;  // [32][1024][PJ] f32 = 3.4 MB

  k_relproj<<<dim3(16, NP), 256, 0, stream>>>(x, relk, P);
  k_fused<<<dim3(512), 512, 0, stream>>>(x, y, vx, vy, relvx, relvy, P, out);
}

// Round 17
// 77.166 us; speedup vs baseline: 1.1261x; 1.1261x over previous
//
#include <hip/hip_runtime.h>
#include <math.h>

#define LQ 1024
#define RS 512          // H*E floats between consecutive l in [B,L,H,E]
#define PJ 26           // padded j-stride for P
#define NP 32
#define ASCALE 0.18033688f   // 0.125 * log2(e)  -> softmax computed in base-2 domain

typedef __attribute__((ext_vector_type(4))) float f32x4;
typedef __attribute__((ext_vector_type(8))) short short8x;

// packed f32x2 -> bf16x2 (RNE) in one VALU op; no HIP API/builtin on gfx950 (T12/m240)
__device__ __forceinline__ unsigned pk2(float a, float b) {
  unsigned r;
  asm("v_cvt_pk_bf16_f32 %0, %1, %2" : "=v"(r) : "v"(a), "v"(b));
  return r;
}

// swizzled LDS byte address for [rows][64 bf16], row stride 128B
__device__ __forceinline__ int swz(int row, int bc) {
  return row * 128 + (bc ^ ((row & 7) << 4));
}
// VT variant: spreads banks when write-rows differ by 4
__device__ __forceinline__ int swzVT(int row, int bc) {
  return row * 128 + (bc ^ ((((row >> 3) ^ row) & 7) << 4));
}

// P[pair, l, j] = (scale*log2e) * dot(x[b,l,h,:], rel_k_table[j,:])
__global__ __launch_bounds__(256) void k_relproj(const float* __restrict__ x,
                                                 const float* __restrict__ relk,
                                                 float* __restrict__ P) {
  __shared__ float rk[25][68];
  __shared__ float xs[64][68];
  const int tid = threadIdx.x;
  const int pair = blockIdx.y, l0 = blockIdx.x * 64;
  const int b = pair >> 3, h = pair & 7;
  for (int i = tid; i < 25 * 64; i += 256) rk[i >> 6][i & 63] = relk[i] * ASCALE;
  const int row = tid >> 2, q = tid & 3;
  const float* xr = x + (size_t)b * 524288 + (size_t)(l0 + row) * RS + h * 64 + q * 16;
#pragma unroll
  for (int i = 0; i < 4; ++i) {
    float4 a = *(const float4*)(xr + i * 4);
    xs[row][q * 16 + i * 4 + 0] = a.x; xs[row][q * 16 + i * 4 + 1] = a.y;
    xs[row][q * 16 + i * 4 + 2] = a.z; xs[row][q * 16 + i * 4 + 3] = a.w;
  }
  __syncthreads();
  float* Pr = P + ((size_t)pair * LQ + l0 + row) * PJ;
  for (int j = q; j < 25; j += 4) {
    float acc = 0.f;
#pragma unroll
    for (int e = 0; e < 64; ++e) acc += xs[row][e] * rk[j][e];
    Pr[j] = acc;
  }
}

// 128-row l-tile, 2 strips/wave. SWAPPED QK: accS[h2][ct][r] = T[s, l] with
// s = t*64+ct*16+rg*4+r, l = l0+h2*64+wv*16+col16 (lane-local l).
// MODE 0: A=x*ASC, B=y, V=v_y, tab=rel_vy, bias=P[l][j]
// MODE 1: A=y*ASC, B=x, V=v_x, tab=rel_vx, bias=P[s][24-j]; j=clip(s-l,-12,12)+12
__global__ __launch_bounds__(256, 2) void k_fused(
    const float* __restrict__ x, const float* __restrict__ y,
    const float* __restrict__ vx, const float* __restrict__ vy,
    const float* __restrict__ relvx, const float* __restrict__ relvy,
    const float* __restrict__ P_g, float* __restrict__ out_g) {
  __shared__ __align__(16) char U[16384];      // A-stage -> 8 per-strip E tiles -> tab
  __shared__ __align__(16) char Bb[2][8192];
  __shared__ __align__(16) char Vb[2][8192];
  __shared__ float W[128 * PJ];

  const int tid = threadIdx.x;
  // bijective remap: p = bx*64 + g  => the 8 blocks of group g share p%8 (same XCD)
  const int p = blockIdx.x;
  const int g = p & 63, bx = p >> 6;        // bx in 0..7
  const int pair = g & 31, mode = g >> 5;
  const int b = pair >> 3, h = pair & 7;
  const int l0 = bx * 128;

  const float* Af = mode ? y : x;
  const float* Bl = mode ? x : y;
  const float* Vv = mode ? vx : vy;
  const float* tb = mode ? relvx : relvy;
  float* outp = out_g + (mode ? 2097152 : 0);

  const float* abase = Af + (size_t)b * 524288 + h * 64;
  const float* bbase = Bl + (size_t)b * 524288 + h * 64;
  const float* vbase = Vv + (size_t)b * 524288 + h * 64;
  const float* Pbase = P_g + (size_t)pair * LQ * PJ;
  float* outb = outp + (size_t)b * 524288 + h * 64;

  const int browA = tid >> 2, bqA = tid & 3;   // A/B staging mapping
  const int vsb = tid >> 4, vdb = tid & 15;    // VT staging mapping

  // ---- prologue: stage A(128 rows, U), B0, VT0; zero W ----
#pragma unroll
  for (int h2 = 0; h2 < 2; ++h2) {
    const float* s = abase + (size_t)(l0 + h2 * 64 + browA) * RS + bqA * 16;
#pragma unroll
    for (int hh = 0; hh < 2; ++hh) {
      float4 a = *(const float4*)(s + hh * 8);
      float4 c = *(const float4*)(s + hh * 8 + 4);
      uint4 u;
      u.x = pk2(a.x * ASCALE, a.y * ASCALE); u.y = pk2(a.z * ASCALE, a.w * ASCALE);
      u.z = pk2(c.x * ASCALE, c.y * ASCALE); u.w = pk2(c.z * ASCALE, c.w * ASCALE);
      *(uint4*)(U + swz(h2 * 64 + browA, bqA * 32 + hh * 16)) = u;
    }
  }
  {
    const float* sb2 = bbase + (size_t)browA * RS + bqA * 16;
#pragma unroll
    for (int hh = 0; hh < 2; ++hh) {
      float4 a = *(const float4*)(sb2 + hh * 8);
      float4 c = *(const float4*)(sb2 + hh * 8 + 4);
      uint4 u;
      u.x = pk2(a.x, a.y); u.y = pk2(a.z, a.w);
      u.z = pk2(c.x, c.y); u.w = pk2(c.z, c.w);
      *(uint4*)(Bb[0] + swz(browA, bqA * 32 + hh * 16)) = u;
    }
    const float* sv = vbase + (size_t)vsb * 4 * RS + vdb * 4;
    float4 r0 = *(const float4*)(sv);
    float4 r1 = *(const float4*)(sv + RS);
    float4 r2 = *(const float4*)(sv + 2 * RS);
    float4 r3 = *(const float4*)(sv + 3 * RS);
    uint2 w2;
    w2.x = pk2(r0.x, r1.x); w2.y = pk2(r2.x, r3.x);
    *(uint2*)(Vb[0] + swzVT(vdb * 4 + 0, vsb * 8)) = w2;
    w2.x = pk2(r0.y, r1.y); w2.y = pk2(r2.y, r3.y);
    *(uint2*)(Vb[0] + swzVT(vdb * 4 + 1, vsb * 8)) = w2;
    w2.x = pk2(r0.z, r1.z); w2.y = pk2(r2.z, r3.z);
    *(uint2*)(Vb[0] + swzVT(vdb * 4 + 2, vsb * 8)) = w2;
    w2.x = pk2(r0.w, r1.w); w2.y = pk2(r2.w, r3.w);
    *(uint2*)(Vb[0] + swzVT(vdb * 4 + 3, vsb * 8)) = w2;
  }
  for (int i = tid; i < 128 * PJ; i += 256) W[i] = 0.f;
  __syncthreads();

  const int lane = tid & 63, wv = tid >> 6;
  const int col16 = lane & 15, rg = lane >> 4;

  // A fragments for both strips (read BEFORE E tiles overwrite U)
  short8x af[2][2];
#pragma unroll
  for (int h2 = 0; h2 < 2; ++h2) {
    af[h2][0] = *(const short8x*)(U + swz(h2 * 64 + wv * 16 + col16, rg * 16));
    af[h2][1] = *(const short8x*)(U + swz(h2 * 64 + wv * 16 + col16, 64 + rg * 16));
  }

  // per-strip lane-l bias pointers (mode 0)
  const float* Prow[2];
  float bL[2] = {0.f, 0.f}, bR[2] = {0.f, 0.f};
#pragma unroll
  for (int h2 = 0; h2 < 2; ++h2)
    Prow[h2] = Pbase + (size_t)(l0 + h2 * 64 + wv * 16 + col16) * PJ;
  if (mode == 0) {
#pragma unroll
    for (int h2 = 0; h2 < 2; ++h2) { bL[h2] = Prow[h2][0]; bR[h2] = Prow[h2][24]; }
  }
  __syncthreads();   // af reads drained before any wave writes E tiles

  f32x4 accO[2][4];
  float wl[2] = {0.f, 0.f}, wr[2] = {0.f, 0.f};
  const f32x4 z4 = {0.f, 0.f, 0.f, 0.f};
#pragma unroll
  for (int h2 = 0; h2 < 2; ++h2)
#pragma unroll
    for (int dt = 0; dt < 4; ++dt) accO[h2][dt] = z4;

  for (int t = 0; t < 16; ++t) {
    const int cb = t & 1, nb = cb ^ 1;
    const int relA = t * 64 - l0;       // strip 0
    const int relB = relA - 64;         // strip 1
    const bool fastA = (relA < -74 || relA > 74);
    const bool fastB = (relB < -74 || relB > 74);

    // ---- issue next-tile B and V loads FIRST (consumed at end of step) ----
    float4 pb[4], pv[4];
    if (t < 15) {
      const float* s = bbase + (size_t)((t + 1) * 64 + browA) * RS + bqA * 16;
#pragma unroll
      for (int i = 0; i < 4; ++i) pb[i] = *(const float4*)(s + i * 4);
      const float* sv2 = vbase + (size_t)((t + 1) * 64 + vsb * 4) * RS + vdb * 4;
#pragma unroll
      for (int k = 0; k < 4; ++k) pv[k] = *(const float4*)(sv2 + (size_t)k * RS);
    }

    // ---- mode-1 fast-path bias (s-dependent; shared by both strips) ----
    float biasf[16];
    if (mode == 1 && (fastA || fastB)) {
      const bool right = fastA ? (relA > 0) : (relB > 0);
#pragma unroll
      for (int ct = 0; ct < 4; ++ct)
#pragma unroll
        for (int r = 0; r < 4; ++r)
          biasf[ct * 4 + r] =
              Pbase[(size_t)(t * 64 + ct * 16 + rg * 4 + r) * PJ + (right ? 0 : 24)];
    }

    // ---- QK (swapped), both strips; B-frags read once ----
    f32x4 accS[2][4];
    const char* bB = Bb[cb];
    __builtin_amdgcn_s_setprio(1);
#pragma unroll
    for (int ct = 0; ct < 4; ++ct) {
      short8x bf0 = *(const short8x*)(bB + swz(ct * 16 + col16, rg * 16));
      short8x bf1 = *(const short8x*)(bB + swz(ct * 16 + col16, 64 + rg * 16));
      f32x4 t0 = __builtin_amdgcn_mfma_f32_16x16x32_bf16(bf0, af[0][0], z4, 0, 0, 0);
      accS[0][ct] = __builtin_amdgcn_mfma_f32_16x16x32_bf16(bf1, af[0][1], t0, 0, 0, 0);
      f32x4 t1 = __builtin_amdgcn_mfma_f32_16x16x32_bf16(bf0, af[1][0], z4, 0, 0, 0);
      accS[1][ct] = __builtin_amdgcn_mfma_f32_16x16x32_bf16(bf1, af[1][1], t1, 0, 0, 0);
    }
    __builtin_amdgcn_s_setprio(0);

    // ---- epilogue per strip: bias, exp2, bucket sums, E -> strip LDS tile ----
#pragma unroll
    for (int h2 = 0; h2 < 2; ++h2) {
      const int rel = h2 ? relB : relA;
      const bool fast = h2 ? fastB : fastA;
      char* ea = U + (wv * 2 + h2) * 2048;
      if (fast) {
        const bool right = rel > 0;
        const float b0 = right ? bR[h2] : bL[h2];
#pragma unroll
        for (int ct = 0; ct < 4; ++ct) {
          float e0 = __builtin_exp2f(accS[h2][ct][0] + (mode ? biasf[ct * 4 + 0] : b0));
          float e1 = __builtin_exp2f(accS[h2][ct][1] + (mode ? biasf[ct * 4 + 1] : b0));
          float e2 = __builtin_exp2f(accS[h2][ct][2] + (mode ? biasf[ct * 4 + 2] : b0));
          float e3 = __builtin_exp2f(accS[h2][ct][3] + (mode ? biasf[ct * 4 + 3] : b0));
          float s4 = (e0 + e1) + (e2 + e3);
          if (right) wr[h2] += s4; else wl[h2] += s4;
          uint2 w2; w2.x = pk2(e0, e1); w2.y = pk2(e2, e3);
          *(uint2*)(ea + swz(col16, ct * 32 + rg * 8)) = w2;
        }
      } else {
#pragma unroll
        for (int ct = 0; ct < 4; ++ct) {
          float e[4];
#pragma unroll
          for (int r = 0; r < 4; ++r) {
            const int sl = ct * 16 + rg * 4 + r;
            const int d = rel + sl - (wv * 16 + col16);
            const int j = (d < -12 ? -12 : (d > 12 ? 12 : d)) + 12;
            const float bias = (mode == 0)
                ? Prow[h2][j]
                : Pbase[(size_t)(t * 64 + sl) * PJ + (24 - j)];
            e[r] = __builtin_exp2f(accS[h2][ct][r] + bias);
            if (d <= -12) wl[h2] += e[r];
            else if (d >= 12) wr[h2] += e[r];
            else W[(h2 * 64 + wv * 16 + col16) * PJ + (d + 12)] = e[r];
          }
          uint2 w2; w2.x = pk2(e[0], e[1]); w2.y = pk2(e[2], e[3]);
          *(uint2*)(ea + swz(col16, ct * 32 + rg * 8)) = w2;
        }
      }
    }

    // ---- wave-local E handoff (E tiles are per-wave; rule #18 pattern) ----
    __builtin_amdgcn_sched_barrier(0);
    asm volatile("s_waitcnt lgkmcnt(0)" ::: "memory");
    __builtin_amdgcn_sched_barrier(0);

    // ---- AV: O += E·V ; V-frags read once, feed both strips ----
    const char* vB = Vb[cb];
    short8x ef[2][2];
#pragma unroll
    for (int h2 = 0; h2 < 2; ++h2) {
      const char* ea = U + (wv * 2 + h2) * 2048;
      ef[h2][0] = *(const short8x*)(ea + swz(col16, rg * 16));
      ef[h2][1] = *(const short8x*)(ea + swz(col16, 64 + rg * 16));
    }
    __builtin_amdgcn_s_setprio(1);
#pragma unroll
    for (int dt = 0; dt < 4; ++dt) {
      short8x v0 = *(const short8x*)(vB + swzVT(dt * 16 + col16, rg * 16));
      short8x v1 = *(const short8x*)(vB + swzVT(dt * 16 + col16, 64 + rg * 16));
      f32x4 t0 = __builtin_amdgcn_mfma_f32_16x16x32_bf16(ef[0][0], v0, accO[0][dt], 0, 0, 0);
      accO[0][dt] = __builtin_amdgcn_mfma_f32_16x16x32_bf16(ef[0][1], v1, t0, 0, 0, 0);
      f32x4 t1 = __builtin_amdgcn_mfma_f32_16x16x32_bf16(ef[1][0], v0, accO[1][dt], 0, 0, 0);
      accO[1][dt] = __builtin_amdgcn_mfma_f32_16x16x32_bf16(ef[1][1], v1, t1, 0, 0, 0);
    }
    __builtin_amdgcn_s_setprio(0);

    // ---- write staged B,V -> nb (loads had the whole step to land) ----
    if (t < 15) {
      uint4 u;
      u.x = pk2(pb[0].x, pb[0].y); u.y = pk2(pb[0].z, pb[0].w);
      u.z = pk2(pb[1].x, pb[1].y); u.w = pk2(pb[1].z, pb[1].w);
      *(uint4*)(Bb[nb] + swz(browA, bqA * 32)) = u;
      u.x = pk2(pb[2].x, pb[2].y); u.y = pk2(pb[2].z, pb[2].w);
      u.z = pk2(pb[3].x, pb[3].y); u.w = pk2(pb[3].z, pb[3].w);
      *(uint4*)(Bb[nb] + swz(browA, bqA * 32 + 16)) = u;
      uint2 w2;
      w2.x = pk2(pv[0].x, pv[1].x); w2.y = pk2(pv[2].x, pv[3].x);
      *(uint2*)(Vb[nb] + swzVT(vdb * 4 + 0, vsb * 8)) = w2;
      w2.x = pk2(pv[0].y, pv[1].y); w2.y = pk2(pv[2].y, pv[3].y);
      *(uint2*)(Vb[nb] + swzVT(vdb * 4 + 1, vsb * 8)) = w2;
      w2.x = pk2(pv[0].z, pv[1].z); w2.y = pk2(pv[2].z, pv[3].z);
      *(uint2*)(Vb[nb] + swzVT(vdb * 4 + 2, vsb * 8)) = w2;
      w2.x = pk2(pv[0].w, pv[1].w); w2.y = pk2(pv[2].w, pv[3].w);
      *(uint2*)(Vb[nb] + swzVT(vdb * 4 + 3, vsb * 8)) = w2;
    }
    __syncthreads();  // single barrier per step
  }

  // ---- tab into U (E region dead now) ----
  float* tabf = (float*)U;
  for (int i = tid; i < 25 * 64; i += 256) tabf[i] = tb[i];
  __syncthreads();

  // ---- per-strip reduce wl/wr across rg groups, redistribute to row lanes ----
  float wlR[2][4], wrR[2][4];
#pragma unroll
  for (int h2 = 0; h2 < 2; ++h2) {
    wl[h2] += __shfl_xor(wl[h2], 16); wl[h2] += __shfl_xor(wl[h2], 32);
    wr[h2] += __shfl_xor(wr[h2], 16); wr[h2] += __shfl_xor(wr[h2], 32);
#pragma unroll
    for (int r = 0; r < 4; ++r) {
      const int src = rg * 4 + r;
      wlR[h2][r] = __shfl(wl[h2], src);
      wrR[h2][r] = __shfl(wr[h2], src);
    }
  }

  // tails (j=0, j=24)
#pragma unroll
  for (int dt = 0; dt < 4; ++dt) {
    const int dd = dt * 16 + col16;
    const float t0 = tabf[dd], t24 = tabf[24 * 64 + dd];
#pragma unroll
    for (int h2 = 0; h2 < 2; ++h2)
#pragma unroll
      for (int r = 0; r < 4; ++r)
        accO[h2][dt][r] += wlR[h2][r] * t0 + wrR[h2][r] * t24;
  }
  // interior j: shared tab reads across strips/r; W reads shared across dt
  float wsum[2][4] = {{0.f, 0.f, 0.f, 0.f}, {0.f, 0.f, 0.f, 0.f}};
#pragma unroll 4
  for (int j = 1; j < 24; ++j) {
    float tj[4];
#pragma unroll
    for (int dt = 0; dt < 4; ++dt) tj[dt] = tabf[j * 64 + dt * 16 + col16];
#pragma unroll
    for (int h2 = 0; h2 < 2; ++h2)
#pragma unroll
      for (int r = 0; r < 4; ++r) {
        const float w = W[(h2 * 64 + wv * 16 + rg * 4 + r) * PJ + j];
        wsum[h2][r] += w;
#pragma unroll
        for (int dt = 0; dt < 4; ++dt) accO[h2][dt][r] += w * tj[dt];
      }
  }
#pragma unroll
  for (int h2 = 0; h2 < 2; ++h2) {
    float inv[4];
#pragma unroll
    for (int r = 0; r < 4; ++r)
      inv[r] = 1.f / (wlR[h2][r] + wrR[h2][r] + wsum[h2][r]);
#pragma unroll
    for (int dt = 0; dt < 4; ++dt)
#pragma unroll
      for (int r = 0; r < 4; ++r) {
        const int row = h2 * 64 + wv * 16 + rg * 4 + r;
        outb[(size_t)(l0 + row) * RS + dt * 16 + col16] = accO[h2][dt][r] * inv[r];
      }
  }
}

extern "C" void kernel_launch(void* const* d_in, const int* in_sizes, int n_in,
                              void* d_out, int out_size, void* d_ws, size_t ws_size,
                              hipStream_t stream) {
  const float* x = (const float*)d_in[0];
  const float* y = (const float*)d_in[1];
  const float* vx = (const float*)d_in[2];
  const float* vy = (const float*)d_in[3];
  const float* relk = (const float*)d_in[4];
  const float* relvx = (const float*)d_in[5];
  const float* relvy = (const float*)d_in[6];
  float* out = (float*)d_out;

  float* P = (float*)d_ws;  // [32][1024][PJ] f32 = 3.4 MB

  k_relproj<<<dim3(16, NP), 256, 0, stream>>>(x, relk, P);
  k_fused<<<dim3(512), 256, 0, stream>>>(x, y, vx, vy, relvx, relvy, P, out);
}